// Round 4
// baseline (1410.176 us; speedup 1.0000x reference)
//
#include <hip/hip_runtime.h>
#include <stdint.h>

typedef unsigned int u32;
typedef unsigned short u16;
typedef float v2f __attribute__((ext_vector_type(2)));

#define NSTEP 16
#define DTS (1.0f/16.0f)

#define TAB_FLAG 0
#define TAB_W2   8
#define TAB_W2M  72
#define TAB_WT   136

__device__ __forceinline__ float b2f(u16 h){ return __uint_as_float(((u32)h) << 16); }
__device__ __forceinline__ float bflo(u32 w){ return __uint_as_float(w << 16); }
__device__ __forceinline__ float bfhi(u32 w){ return __uint_as_float(w & 0xffff0000u); }
__device__ __forceinline__ u32 f2b(float f){
  u32 u = __float_as_uint(f);
  return (u + 0x7fffu + ((u >> 16) & 1u)) >> 16;   // RNE to bf16
}
__host__ __device__ constexpr int TRI(int i, int j){ return i*7 - (i*(i-1))/2 + (j-i-1); }

__device__ __forceinline__ v2f vfma(v2f a, v2f b, v2f c){ return __builtin_elementwise_fma(a, b, c); }
// dot of 8-element rows held as 4 v2f each
__device__ __forceinline__ float dot8(const v2f* a, const v2f* u){
  v2f d = a[0] * u[0];
  d = vfma(a[1], u[1], d);
  d = vfma(a[2], u[2], d);
  d = vfma(a[3], u[3], d);
  return d.x + d.y;
}

// ws (floats): [0] dtype flag (1.0 = bf16 inputs, 0.0 = fp32)
//              [8..71] W2 ; [72..135] M = W2 - W2^T
//              [136 + s*32 + e] antisym(W0 + t(s)*W1) upper-tri, e<28, s = step*4+stage
__global__ void prep_kernel(const void* __restrict__ W0v, const void* __restrict__ W1v,
                            const void* __restrict__ W2v, float* __restrict__ ws)
{
  __shared__ int sflag;
  __shared__ float sW0[64], sW1[64], sW2[64];
  int t = threadIdx.x;

  if (t == 0) {
    const u16* w2h = (const u16*)W2v;
    int ok = 1;
    for (int x = 0; x < 64; ++x) {
      float v = b2f(w2h[x]);
      if (!(v > -1024.0f && v < 1024.0f)) { ok = 0; break; }
    }
    sflag = ok;
    ws[TAB_FLAG] = (float)ok;
  }
  __syncthreads();
  int isbf = sflag;

  if (t < 64) {
    if (isbf) {
      sW0[t] = b2f(((const u16*)W0v)[t]);
      sW1[t] = b2f(((const u16*)W1v)[t]);
      sW2[t] = b2f(((const u16*)W2v)[t]);
    } else {
      sW0[t] = ((const float*)W0v)[t];
      sW1[t] = ((const float*)W1v)[t];
      sW2[t] = ((const float*)W2v)[t];
    }
  }
  __syncthreads();

  if (t < 64) {
    int i = t >> 3, j = t & 7;
    ws[TAB_W2  + t] = sW2[t];
    ws[TAB_W2M + t] = sW2[t] - sW2[j*8+i];
  }
  for (int idx = t; idx < 64*28; idx += 256) {
    int s = idx / 28;
    int e = idx - s*28;
    int i = 0, r = e;
    while (r >= 7 - i) { r -= 7 - i; ++i; }
    int j = i + 1 + r;
    int step = s >> 2, st = s & 3;
    float toff = (st == 0) ? 0.0f : ((st == 3) ? 1.0f : 0.5f);
    float tt = ((float)step + toff) * DTS;
    float w0a = 0.5f*(sW0[i*8+j] - sW0[j*8+i]);
    float w1a = 0.5f*(sW1[i*8+j] - sW1[j*8+i]);
    ws[TAB_WT + s*32 + e] = fmaf(tt, w1a, w0a);
  }
}

__global__ __launch_bounds__(256, 2) void flow_kernel(
    const void* __restrict__ U0v, const void* __restrict__ EPSv,
    const float* __restrict__ ws, void* __restrict__ outv, int B)
{
  // per-thread private stash: V rows and E rows as 8 bf16 (one uint4) each.
  // No cross-thread sharing -> no barriers needed (same-wave lgkmcnt ordering).
  __shared__ uint4 sV[8][256];
  __shared__ uint4 sE[8][256];

  const int tid = threadIdx.x;
  const int b = blockIdx.x * 256 + tid;
  if (b >= B) return;
  const int isbf = (ws[TAB_FLAG] != 0.0f);

  const v2f* W2p = (const v2f*)(ws + TAB_W2);    // W2 row k, col-pair jp: W2p[k*4+jp]
  const v2f* Mp  = (const v2f*)(ws + TAB_W2M);   // M  row k, col-pair mp

  v2f U2[32];

  // ---- setup: load U; stash V rows (bf16) + E rows (E = V*M, bf16) to LDS ----
  if (isbf) {
    const uint4* pu = (const uint4*)((const u16*)U0v + (size_t)b*64);
    const uint4* pv = (const uint4*)((const u16*)EPSv + (size_t)b*64);
    #pragma unroll
    for (int q = 0; q < 8; ++q) {
      uint4 xu = pu[q];
      U2[4*q+0] = (v2f){bflo(xu.x), bfhi(xu.x)};
      U2[4*q+1] = (v2f){bflo(xu.y), bfhi(xu.y)};
      U2[4*q+2] = (v2f){bflo(xu.z), bfhi(xu.z)};
      U2[4*q+3] = (v2f){bflo(xu.w), bfhi(xu.w)};
    }
    #pragma unroll
    for (int r = 0; r < 8; ++r) {
      uint4 xv = pv[r];
      sV[r][tid] = xv;                       // exact (input already bf16)
      v2f Vr2[4] = { (v2f){bflo(xv.x), bfhi(xv.x)}, (v2f){bflo(xv.y), bfhi(xv.y)},
                     (v2f){bflo(xv.z), bfhi(xv.z)}, (v2f){bflo(xv.w), bfhi(xv.w)} };
      // E row r: E_rm = sum_k V_rk * M_km
      v2f e[4];
      #pragma unroll
      for (int mp = 0; mp < 4; ++mp) {
        v2f a = (v2f){Vr2[0].x, Vr2[0].x} * Mp[0*4+mp];
        #pragma unroll
        for (int k = 1; k < 8; ++k) {
          float vk = (k & 1) ? Vr2[k>>1].y : Vr2[k>>1].x;
          a = vfma((v2f){vk, vk}, Mp[k*4+mp], a);
        }
        e[mp] = a;
      }
      uint4 xe;
      xe.x = f2b(e[0].x) | (f2b(e[0].y) << 16);
      xe.y = f2b(e[1].x) | (f2b(e[1].y) << 16);
      xe.z = f2b(e[2].x) | (f2b(e[2].y) << 16);
      xe.w = f2b(e[3].x) | (f2b(e[3].y) << 16);
      sE[r][tid] = xe;
    }
  } else {
    const float4* pu = (const float4*)((const float*)U0v + (size_t)b*64);
    const float4* pv = (const float4*)((const float*)EPSv + (size_t)b*64);
    #pragma unroll
    for (int q = 0; q < 16; ++q) {
      float4 xu = pu[q];
      U2[2*q+0] = (v2f){xu.x, xu.y};  U2[2*q+1] = (v2f){xu.z, xu.w};
    }
    #pragma unroll
    for (int r = 0; r < 8; ++r) {
      float4 a0 = pv[2*r], a1 = pv[2*r+1];
      v2f Vr2[4] = { (v2f){a0.x, a0.y}, (v2f){a0.z, a0.w}, (v2f){a1.x, a1.y}, (v2f){a1.z, a1.w} };
      uint4 xv;
      xv.x = f2b(Vr2[0].x) | (f2b(Vr2[0].y) << 16);
      xv.y = f2b(Vr2[1].x) | (f2b(Vr2[1].y) << 16);
      xv.z = f2b(Vr2[2].x) | (f2b(Vr2[2].y) << 16);
      xv.w = f2b(Vr2[3].x) | (f2b(Vr2[3].y) << 16);
      sV[r][tid] = xv;
      v2f e[4];
      #pragma unroll
      for (int mp = 0; mp < 4; ++mp) {
        v2f a = (v2f){Vr2[0].x, Vr2[0].x} * Mp[0*4+mp];
        #pragma unroll
        for (int k = 1; k < 8; ++k) {
          float vk = (k & 1) ? Vr2[k>>1].y : Vr2[k>>1].x;
          a = vfma((v2f){vk, vk}, Mp[k*4+mp], a);
        }
        e[mp] = a;
      }
      uint4 xe;
      xe.x = f2b(e[0].x) | (f2b(e[0].y) << 16);
      xe.y = f2b(e[1].x) | (f2b(e[1].y) << 16);
      xe.z = f2b(e[2].x) | (f2b(e[2].y) << 16);
      xe.w = f2b(e[3].x) | (f2b(e[3].y) << 16);
      sE[r][tid] = xe;
    }
  }

  float lj = 0.0f;

  #pragma unroll 1
  for (int step = 0; step < NSTEP; ++step) {
    v2f Us2[32], acc2[32];
    #pragma unroll
    for (int x = 0; x < 32; ++x) { Us2[x] = U2[x]; acc2[x] = (v2f){0.0f, 0.0f}; }

    #pragma unroll 1
    for (int stage = 0; stage < 4; ++stage) {
      const float* wt = ws + TAB_WT + (size_t)(((step << 2) | stage) << 5);

      // ---- logj: Ssum = sum_{i<j} Delta_ij * Gamma_ij, row-streamed ----
      // Delta_ij = dot(V_i,U_j) - dot(U_i,V_j) ; Gamma_ij = dot(E_i,U_j) - dot(E_j,U_i)
      float Dp[28], Gp[28];
      float Ssum = 0.0f;
      #pragma unroll
      for (int r = 0; r < 8; ++r) {
        uint4 xv = sV[r][tid];
        uint4 xe = sE[r][tid];
        v2f Vr2[4] = { (v2f){bflo(xv.x), bfhi(xv.x)}, (v2f){bflo(xv.y), bfhi(xv.y)},
                       (v2f){bflo(xv.z), bfhi(xv.z)}, (v2f){bflo(xv.w), bfhi(xv.w)} };
        v2f Er2[4] = { (v2f){bflo(xe.x), bfhi(xe.x)}, (v2f){bflo(xe.y), bfhi(xe.y)},
                       (v2f){bflo(xe.z), bfhi(xe.z)}, (v2f){bflo(xe.w), bfhi(xe.w)} };
        #pragma unroll
        for (int j = 0; j < 8; ++j) {
          if (j == r) continue;
          float dv = dot8(Vr2, &U2[j*4]);   // dot(V_r, U_j)
          float de = dot8(Er2, &U2[j*4]);   // dot(E_r, U_j)
          if (j > r) {
            Dp[TRI(r,j)] = dv;              // = dot(V_i,U_j) for pair (i=r, j)
            Gp[TRI(r,j)] = de;              // = dot(E_i,U_j)
          } else {
            // pair (i=j, j=r): Delta = Dp - dot(U_i,V_r) = Dp - dv ; Gamma = Gp - de
            Ssum = fmaf(Dp[TRI(j,r)] - dv, Gp[TRI(j,r)] - de, Ssum);
          }
        }
      }
      float cl = (stage == 1 || stage == 2) ? (DTS/6.0f) : (DTS/12.0f); // dt/6 * w * 0.5
      lj = fmaf(cl, Ssum, lj);

      // ---- F upper tri, row-streamed A: F_ij = wt_ij + 0.5*(dot(A_i,U_j)-dot(A_j,U_i)) ----
      float Fu[28];
      #pragma unroll
      for (int r = 0; r < 8; ++r) {
        // A row r = U_r * W2
        v2f Ar[4];
        #pragma unroll
        for (int jp = 0; jp < 4; ++jp) {
          float u0 = U2[r*4].x;
          v2f a = (v2f){u0, u0} * W2p[0*4+jp];
          #pragma unroll
          for (int k = 1; k < 8; ++k) {
            float uk = (k & 1) ? U2[r*4 + (k>>1)].y : U2[r*4 + (k>>1)].x;
            a = vfma((v2f){uk, uk}, W2p[k*4+jp], a);
          }
          Ar[jp] = a;
        }
        #pragma unroll
        for (int j = 0; j < 8; ++j) {
          if (j == r) continue;
          float da = dot8(Ar, &U2[j*4]);    // dot(A_r, U_j)
          if (j > r) Fu[TRI(r,j)] = fmaf(0.5f, da, wt[TRI(r,j)]);
          else       Fu[TRI(j,r)] = fmaf(-0.5f, da, Fu[TRI(j,r)]);
        }
      }

      // ---- K = F*U column-pair-wise; acc += w*K; stage<3: U = Us + cs*K ----
      float wa = (stage == 1 || stage == 2) ? 2.0f : 1.0f;
      float cs = (stage == 2) ? DTS : (0.5f*DTS);
      #pragma unroll
      for (int jp = 0; jp < 4; ++jp) {
        v2f kc[8];
        #pragma unroll
        for (int i = 0; i < 8; ++i) {
          const int k0 = (i == 0) ? 1 : 0;
          float f0 = (i < k0) ? Fu[TRI(i<k0?i:k0, i<k0?k0:i)] : -Fu[TRI(i<k0?i:k0, i<k0?k0:i)];
          v2f s2 = (v2f){f0, f0} * U2[k0*4+jp];
          #pragma unroll
          for (int k = 0; k < 8; ++k) {
            if (k == i || k == k0) continue;
            float fk = (i < k) ? Fu[TRI(i<k?i:k, i<k?k:i)] : -Fu[TRI(i<k?i:k, i<k?k:i)];
            s2 = vfma((v2f){fk, fk}, U2[k*4+jp], s2);
          }
          kc[i] = s2;
        }
        #pragma unroll
        for (int i = 0; i < 8; ++i) {
          acc2[i*4+jp] = vfma((v2f){wa, wa}, kc[i], acc2[i*4+jp]);
          if (stage < 3) U2[i*4+jp] = vfma((v2f){cs, cs}, kc[i], Us2[i*4+jp]);
        }
      }
    }

    #pragma unroll
    for (int x = 0; x < 32; ++x) U2[x] = vfma((v2f){DTS/6.0f, DTS/6.0f}, acc2[x], Us2[x]);
  }

  // ---- store ----
  if (isbf) {
    u16* outU = (u16*)outv;
    uint4* po = (uint4*)(outU + (size_t)b*64);
    #pragma unroll
    for (int q = 0; q < 8; ++q) {
      uint4 o;
      o.x = f2b(U2[4*q+0].x) | (f2b(U2[4*q+0].y) << 16);
      o.y = f2b(U2[4*q+1].x) | (f2b(U2[4*q+1].y) << 16);
      o.z = f2b(U2[4*q+2].x) | (f2b(U2[4*q+2].y) << 16);
      o.w = f2b(U2[4*q+3].x) | (f2b(U2[4*q+3].y) << 16);
      po[q] = o;
    }
    outU[(size_t)B*64 + b] = (u16)f2b(lj);
  } else {
    float* outU = (float*)outv;
    float4* po = (float4*)(outU + (size_t)b*64);
    #pragma unroll
    for (int q = 0; q < 16; ++q) {
      float4 o;
      o.x = U2[2*q].x; o.y = U2[2*q].y; o.z = U2[2*q+1].x; o.w = U2[2*q+1].y;
      po[q] = o;
    }
    outU[(size_t)B*64 + b] = lj;
  }
}

extern "C" void kernel_launch(void* const* d_in, const int* in_sizes, int n_in,
                              void* d_out, int out_size, void* d_ws, size_t ws_size,
                              hipStream_t stream) {
  const void* U0  = d_in[0];
  const void* EPS = d_in[1];
  const void* W0  = d_in[2];
  const void* W1  = d_in[3];
  const void* W2  = d_in[4];
  float* ws = (float*)d_ws;
  int B = in_sizes[0] / 64;

  hipLaunchKernelGGL(prep_kernel, dim3(1), dim3(256), 0, stream, W0, W1, W2, ws);
  hipLaunchKernelGGL(flow_kernel, dim3((B + 255) / 256), dim3(256), 0, stream,
                     U0, EPS, ws, d_out, B);
}

// Round 5
// 622.104 us; speedup vs baseline: 2.2668x; 2.2668x over previous
//
#include <hip/hip_runtime.h>
#include <stdint.h>

typedef unsigned int u32;
typedef unsigned short u16;
typedef _Float16 h2 __attribute__((ext_vector_type(2)));

#define NSTEP 16
#define DTS (1.0f/16.0f)

// ws layout (float index): [0] dtype flag; [8..71] M = W2 - W2^T (fp32);
// [72..103] W2 columns packed half2 (u32 bits): w2c[j*4+kk] = pk(W2[2kk][j], W2[2kk+1][j]);
// [112 + s*32 + e] antisym(W0 + t(s)*W1) upper-tri (fp32), e<28, s = step*4+stage
#define TAB_FLAG 0
#define TAB_W2M  8
#define TAB_W2C  72
#define TAB_WT   112

__device__ __forceinline__ float b2f(u16 h){ return __uint_as_float(((u32)h) << 16); }
__device__ __forceinline__ float bflo(u32 w){ return __uint_as_float(w << 16); }
__device__ __forceinline__ float bfhi(u32 w){ return __uint_as_float(w & 0xffff0000u); }
__device__ __forceinline__ u32 f2b(float f){
  u32 u = __float_as_uint(f);
  return (u + 0x7fffu + ((u >> 16) & 1u)) >> 16;   // RNE to bf16
}
__host__ __device__ constexpr int TRI(int i, int j){ return i*7 - (i*(i-1))/2 + (j-i-1); }

__device__ __forceinline__ u32 pkh(float a, float b){
  return __builtin_bit_cast(u32, __builtin_amdgcn_cvt_pkrtz(a, b));
}
// 8-length dot of half2-packed rows (4 u32 each), fp32 accumulate via v_dot2_f32_f16
__device__ __forceinline__ float dot8h(const u32* a, const u32* b){
  float s = __builtin_amdgcn_fdot2(__builtin_bit_cast(h2, a[0]), __builtin_bit_cast(h2, b[0]), 0.0f, false);
  s = __builtin_amdgcn_fdot2(__builtin_bit_cast(h2, a[1]), __builtin_bit_cast(h2, b[1]), s, false);
  s = __builtin_amdgcn_fdot2(__builtin_bit_cast(h2, a[2]), __builtin_bit_cast(h2, b[2]), s, false);
  s = __builtin_amdgcn_fdot2(__builtin_bit_cast(h2, a[3]), __builtin_bit_cast(h2, b[3]), s, false);
  return s;
}
// F element with antisymmetry (compile-time i,k only)
__device__ __forceinline__ float Fel(const float* Fu, int i, int k){
  if (i == k) return 0.0f;
  return (i < k) ? Fu[TRI(i,k)] : -Fu[TRI(k,i)];
}

__global__ void prep_kernel(const void* __restrict__ W0v, const void* __restrict__ W1v,
                            const void* __restrict__ W2v, float* __restrict__ ws)
{
  __shared__ int sflag;
  __shared__ float sW0[64], sW1[64], sW2[64];
  int t = threadIdx.x;

  if (t == 0) {
    const u16* w2h = (const u16*)W2v;
    int ok = 1;
    for (int x = 0; x < 64; ++x) {
      float v = b2f(w2h[x]);
      if (!(v > -1024.0f && v < 1024.0f)) { ok = 0; break; }
    }
    sflag = ok;
    ws[TAB_FLAG] = (float)ok;
  }
  __syncthreads();
  int isbf = sflag;

  if (t < 64) {
    if (isbf) {
      sW0[t] = b2f(((const u16*)W0v)[t]);
      sW1[t] = b2f(((const u16*)W1v)[t]);
      sW2[t] = b2f(((const u16*)W2v)[t]);
    } else {
      sW0[t] = ((const float*)W0v)[t];
      sW1[t] = ((const float*)W1v)[t];
      sW2[t] = ((const float*)W2v)[t];
    }
  }
  __syncthreads();

  if (t < 64) {
    int i = t >> 3, j = t & 7;
    ws[TAB_W2M + t] = sW2[t] - sW2[j*8+i];
  }
  if (t < 32) {
    int j = t >> 2, kk = t & 3;
    ((u32*)ws)[TAB_W2C + t] = pkh(sW2[(2*kk)*8 + j], sW2[(2*kk+1)*8 + j]);
  }
  for (int idx = t; idx < 64*28; idx += 256) {
    int s = idx / 28;
    int e = idx - s*28;
    int i = 0, r = e;
    while (r >= 7 - i) { r -= 7 - i; ++i; }
    int j = i + 1 + r;
    int step = s >> 2, st = s & 3;
    float toff = (st == 0) ? 0.0f : ((st == 3) ? 1.0f : 0.5f);
    float tt = ((float)step + toff) * DTS;
    float w0a = 0.5f*(sW0[i*8+j] - sW0[j*8+i]);
    float w1a = 0.5f*(sW1[i*8+j] - sW1[j*8+i]);
    ws[TAB_WT + s*32 + e] = fmaf(tt, w1a, w0a);
  }
}

__global__ void __attribute__((amdgpu_flat_work_group_size(256,256), amdgpu_waves_per_eu(1,1)))
flow_kernel(const void* __restrict__ U0v, const void* __restrict__ EPSv,
            const float* __restrict__ ws, void* __restrict__ outv, int B)
{
  const int b = blockIdx.x * 256 + threadIdx.x;
  if (b >= B) return;
  const int isbf = (ws[TAB_FLAG] != 0.0f);

  float U[64];
  u32 Vh[32], Eh[32];   // V rows and E rows, half2-packed (per-batch constant)

  // ---- setup: decode U, V; E = V*M (fp32); pack V,E to half2 ----
  {
    float V[64];
    if (isbf) {
      const uint4* pu = (const uint4*)((const u16*)U0v + (size_t)b*64);
      const uint4* pv = (const uint4*)((const u16*)EPSv + (size_t)b*64);
      #pragma unroll
      for (int q = 0; q < 8; ++q) {
        uint4 xu = pu[q];
        uint4 xv = pv[q];
        U[8*q+0]=bflo(xu.x); U[8*q+1]=bfhi(xu.x);
        U[8*q+2]=bflo(xu.y); U[8*q+3]=bfhi(xu.y);
        U[8*q+4]=bflo(xu.z); U[8*q+5]=bfhi(xu.z);
        U[8*q+6]=bflo(xu.w); U[8*q+7]=bfhi(xu.w);
        V[8*q+0]=bflo(xv.x); V[8*q+1]=bfhi(xv.x);
        V[8*q+2]=bflo(xv.y); V[8*q+3]=bfhi(xv.y);
        V[8*q+4]=bflo(xv.z); V[8*q+5]=bfhi(xv.z);
        V[8*q+6]=bflo(xv.w); V[8*q+7]=bfhi(xv.w);
      }
    } else {
      const float4* pu = (const float4*)((const float*)U0v + (size_t)b*64);
      const float4* pv = (const float4*)((const float*)EPSv + (size_t)b*64);
      #pragma unroll
      for (int q = 0; q < 16; ++q) {
        float4 xu = pu[q];
        float4 xv = pv[q];
        U[4*q+0]=xu.x; U[4*q+1]=xu.y; U[4*q+2]=xu.z; U[4*q+3]=xu.w;
        V[4*q+0]=xv.x; V[4*q+1]=xv.y; V[4*q+2]=xv.z; V[4*q+3]=xv.w;
      }
    }
    const float* M = ws + TAB_W2M;
    #pragma unroll
    for (int i = 0; i < 8; ++i) {
      float e[8];
      #pragma unroll
      for (int j = 0; j < 8; ++j) {
        float s = V[i*8+0] * M[0*8+j];
        #pragma unroll
        for (int k = 1; k < 8; ++k) s = fmaf(V[i*8+k], M[k*8+j], s);
        e[j] = s;
      }
      #pragma unroll
      for (int kk = 0; kk < 4; ++kk) {
        Vh[i*4+kk] = pkh(V[i*8+2*kk], V[i*8+2*kk+1]);
        Eh[i*4+kk] = pkh(e[2*kk], e[2*kk+1]);
      }
    }
  }

  // uniform packed W2 columns (compiler keeps these scalar)
  u32 w2c[32];
  #pragma unroll
  for (int x = 0; x < 32; ++x) w2c[x] = ((const u32*)ws)[TAB_W2C + x];

  float lj = 0.0f;

  #pragma unroll 1
  for (int step = 0; step < NSTEP; ++step) {
    float Us[64], acc[64];
    #pragma unroll
    for (int x = 0; x < 64; ++x) { Us[x] = U[x]; acc[x] = 0.0f; }

    #pragma unroll 1
    for (int stage = 0; stage < 4; ++stage) {
      const float* wt = ws + TAB_WT + (size_t)(((step << 2) | stage) << 5);

      // pack current-stage U rows to half2
      u32 Uh[32];
      #pragma unroll
      for (int e = 0; e < 32; ++e) Uh[e] = pkh(U[2*e], U[2*e+1]);

      // ---- logj: Ssum = sum_{i<j} Delta_ij * Gamma_ij ----
      // Delta_ij = dot(V_i,U_j) - dot(V_j,U_i) ; Gamma_ij = dot(E_i,U_j) - dot(E_j,U_i)
      float Dp[28], Gp[28];
      float Ssum = 0.0f;
      #pragma unroll
      for (int r = 0; r < 8; ++r) {
        #pragma unroll
        for (int m = 0; m < 8; ++m) {
          if (m == r) continue;
          float dv = dot8h(Vh + r*4, Uh + m*4);   // dot(V_r, U_m)
          float de = dot8h(Eh + r*4, Uh + m*4);   // dot(E_r, U_m)
          if (m > r) {
            Dp[TRI(r,m)] = dv;
            Gp[TRI(r,m)] = de;
          } else {
            Ssum = fmaf(Dp[TRI(m,r)] - dv, Gp[TRI(m,r)] - de, Ssum);
          }
        }
      }
      float cl = (stage == 1 || stage == 2) ? (DTS/6.0f) : (DTS/12.0f); // dt/6 * w * 0.5
      lj = fmaf(cl, Ssum, lj);

      // ---- F upper tri, row-streamed: F_ij = wt_ij + 0.5*(dot(A_i,U_j)-dot(A_j,U_i)) ----
      float Fu[28];
      #pragma unroll
      for (int r = 0; r < 8; ++r) {
        float ar[8];
        #pragma unroll
        for (int j = 0; j < 8; ++j) ar[j] = dot8h(Uh + r*4, w2c + j*4);  // A_rj
        u32 Ah[4];
        #pragma unroll
        for (int kk = 0; kk < 4; ++kk) Ah[kk] = pkh(ar[2*kk], ar[2*kk+1]);
        #pragma unroll
        for (int j = 0; j < 8; ++j) {
          if (j == r) continue;
          float da = dot8h(Ah, Uh + j*4);         // dot(A_r, U_j)
          if (j > r) Fu[TRI(r,j)] = fmaf(0.5f, da, wt[TRI(r,j)]);
          else       Fu[TRI(j,r)] = fmaf(-0.5f, da, Fu[TRI(j,r)]);
        }
      }

      // ---- K = F*U: pack F rows + U columns, dot per entry ----
      u32 Fh[32], Uc[32];
      #pragma unroll
      for (int i = 0; i < 8; ++i)
        #pragma unroll
        for (int kk = 0; kk < 4; ++kk)
          Fh[i*4+kk] = pkh(Fel(Fu, i, 2*kk), Fel(Fu, i, 2*kk+1));
      #pragma unroll
      for (int j = 0; j < 8; ++j)
        #pragma unroll
        for (int kk = 0; kk < 4; ++kk)
          Uc[j*4+kk] = pkh(U[(2*kk)*8+j], U[(2*kk+1)*8+j]);

      float wa = (stage == 1 || stage == 2) ? 2.0f : 1.0f;
      float cs = (stage == 2) ? DTS : (0.5f*DTS);
      #pragma unroll
      for (int i = 0; i < 8; ++i) {
        #pragma unroll
        for (int j = 0; j < 8; ++j) {
          float kv = dot8h(Fh + i*4, Uc + j*4);
          acc[i*8+j] = fmaf(wa, kv, acc[i*8+j]);
          if (stage < 3) U[i*8+j] = fmaf(cs, kv, Us[i*8+j]);
        }
      }
    }

    #pragma unroll
    for (int x = 0; x < 64; ++x) U[x] = fmaf(DTS/6.0f, acc[x], Us[x]);
  }

  // ---- store ----
  if (isbf) {
    u16* outU = (u16*)outv;
    uint4* po = (uint4*)(outU + (size_t)b*64);
    #pragma unroll
    for (int q = 0; q < 8; ++q) {
      uint4 o;
      o.x = f2b(U[8*q+0]) | (f2b(U[8*q+1]) << 16);
      o.y = f2b(U[8*q+2]) | (f2b(U[8*q+3]) << 16);
      o.z = f2b(U[8*q+4]) | (f2b(U[8*q+5]) << 16);
      o.w = f2b(U[8*q+6]) | (f2b(U[8*q+7]) << 16);
      po[q] = o;
    }
    outU[(size_t)B*64 + b] = (u16)f2b(lj);
  } else {
    float* outU = (float*)outv;
    float4* po = (float4*)(outU + (size_t)b*64);
    #pragma unroll
    for (int q = 0; q < 16; ++q) {
      float4 o;
      o.x = U[4*q+0]; o.y = U[4*q+1]; o.z = U[4*q+2]; o.w = U[4*q+3];
      po[q] = o;
    }
    outU[(size_t)B*64 + b] = lj;
  }
}

extern "C" void kernel_launch(void* const* d_in, const int* in_sizes, int n_in,
                              void* d_out, int out_size, void* d_ws, size_t ws_size,
                              hipStream_t stream) {
  const void* U0  = d_in[0];
  const void* EPS = d_in[1];
  const void* W0  = d_in[2];
  const void* W1  = d_in[3];
  const void* W2  = d_in[4];
  float* ws = (float*)d_ws;
  int B = in_sizes[0] / 64;

  hipLaunchKernelGGL(prep_kernel, dim3(1), dim3(256), 0, stream, W0, W1, W2, ws);
  hipLaunchKernelGGL(flow_kernel, dim3((B + 255) / 256), dim3(256), 0, stream,
                     U0, EPS, ws, d_out, B);
}